// Round 14
// baseline (271.048 us; speedup 1.0000x reference)
//
#include <hip/hip_runtime.h>
#include <hip/hip_bf16.h>

#define NNODES 100000
#define NEDGES 1600000
#define INF 512
#define OUTF 128
#define NB 391          // buckets of 256 nodes: bucket = dst >> 8
#define BCAP 5120       // mean 4096, sigma ~64 -> 16 sigma headroom
#define SEG 2048        // edges per block in bucket_kernel (782 blocks)
#define BK2 64          // gemm k-step (floats) -> 256 B contiguous per row
#define NK2 (INF / BK2) // 8 steps

typedef __attribute__((ext_vector_type(8))) __bf16 bf16x8;
typedef __attribute__((ext_vector_type(4))) float f32x4;

typedef const __attribute__((address_space(1))) unsigned int* gas_ptr;
typedef __attribute__((address_space(3))) unsigned int* las_ptr;

__device__ __forceinline__ void gload_lds16(const void* g, void* l) {
  __builtin_amdgcn_global_load_lds((gas_ptr)g, (las_ptr)l, 16, 0, 0);
}

// ---------------- weight f32 [512][128] -> bf16 fragment/lane-ordered -------
// short idx = kb*4096 + c8*512 + lane*8 + j  (lane = lg*16+l15)
//   value   = W[kb*32 + lg*8 + j][c8*16 + l15]
__global__ void wt_kernel(const float* __restrict__ w, unsigned short* __restrict__ wta) {
  int i = blockIdx.x * blockDim.x + threadIdx.x;   // 0..8191 int4s
  if (i >= 8192) return;
  int lane = i & 63;
  int c8   = (i >> 6) & 7;
  int kb   = i >> 9;
  int n = c8 * 16 + (lane & 15);
  int kbase = kb * 32 + (lane >> 4) * 8;
  unsigned short tmp[8];
#pragma unroll
  for (int j = 0; j < 8; ++j) {
    __bf16 b = (__bf16)(w[(size_t)(kbase + j) * OUTF + n]);
    tmp[j] = __builtin_bit_cast(unsigned short, b);
  }
  ((int4*)wta)[i] = *(int4*)tmp;
}

// ---------------- bucket edges by dst>>8, histogram src out-degree ----------
__global__ __launch_bounds__(256) void bucket_kernel(
    const int* __restrict__ src, const int* __restrict__ dst,
    const float* __restrict__ ew, int* __restrict__ out_cnt,
    int* __restrict__ bucket_cnt, int2* __restrict__ bucket) {
  __shared__ int hist[NB];
  __shared__ int base[NB];
  int t = threadIdx.x;
  for (int i = t; i < NB; i += 256) hist[i] = 0;
  __syncthreads();
  int e0 = blockIdx.x * SEG;
  int e1 = min(e0 + SEG, NEDGES);
  for (int e = e0 + t; e < e1; e += 256) {
    atomicAdd(&out_cnt[src[e]], 1);
    atomicAdd(&hist[dst[e] >> 8], 1);
  }
  __syncthreads();
  for (int i = t; i < NB; i += 256) {
    int c = hist[i];
    base[i] = c ? atomicAdd(&bucket_cnt[i], c) : 0;
    hist[i] = 0;                       // reuse as cursor
  }
  __syncthreads();
  for (int e = e0 + t; e < e1; e += 256) {
    int d = dst[e];
    int b = d >> 8;
    int r = atomicAdd(&hist[b], 1);
    int2 en;
    en.x = ((d & 255) << 17) | src[e];  // src < 2^17
    en.y = __float_as_int(ew[e]);
    bucket[(size_t)b * BCAP + base[b] + r] = en;
  }
}

// ---------------- exclusive scan of bucket counts (1 block) -----------------
__global__ __launch_bounds__(512) void bscan_kernel(const int* __restrict__ bucket_cnt,
                                                    int* __restrict__ bucket_base,
                                                    int* __restrict__ rowptr) {
  __shared__ int s[512];
  int t = threadIdx.x;
  int v = (t < NB) ? bucket_cnt[t] : 0;
  s[t] = v;
  __syncthreads();
  for (int off = 1; off < 512; off <<= 1) {
    int x = (t >= off) ? s[t - off] : 0;
    __syncthreads();
    s[t] += x;
    __syncthreads();
  }
  if (t < NB) bucket_base[t] = s[t] - v;
  if (t == 0) rowptr[NNODES] = NEDGES;
}

// ---------------- bucket -> CSR (rowptr + epair) ----------------------------
__global__ __launch_bounds__(256) void csr_kernel(
    const int* __restrict__ bucket_cnt, const int* __restrict__ bucket_base,
    const int2* __restrict__ bucket, int* __restrict__ rowptr,
    int2* __restrict__ epair) {
  __shared__ int hist[256];
  __shared__ int cur[256];
  int b = blockIdx.x;
  int t = threadIdx.x;
  int nb = bucket_cnt[b];
  int bbase = bucket_base[b];
  const int2* bk = bucket + (size_t)b * BCAP;
  hist[t] = 0;
  __syncthreads();
  for (int i = t; i < nb; i += 256) atomicAdd(&hist[bk[i].x >> 17], 1);
  __syncthreads();
  int v = hist[t];
  for (int off = 1; off < 256; off <<= 1) {
    int x = (t >= off) ? hist[t - off] : 0;
    __syncthreads();
    hist[t] += x;
    __syncthreads();
  }
  int excl = hist[t] - v;
  int node = b * 256 + t;
  if (node < NNODES) rowptr[node] = bbase + excl;
  cur[t] = excl;
  __syncthreads();
  for (int i = t; i < nb; i += 256) {
    int2 en = bk[i];
    int nl = en.x >> 17;
    int r = atomicAdd(&cur[nl], 1);
    epair[bbase + r] = make_int2(en.x & 0x1FFFF, en.y);
  }
}

// ---------------- h = (feat * rsqrt(out_deg)) @ W, BK=64 LDS MFMA -----------
// 64-row x 128-col tile, BK=64 (8 K-steps), 4 waves (one 16-row frag each).
// A: dbuf [64][64] f32 (16 KB each), 16-chunk XOR swizzle (chunk' = chunk ^
//    (row&15)) applied via pre-swizzled global source, linear LDS dest.
// B: dbuf 16 KB bf16 lane-ordered (2 consecutive wta kb-blocks per step).
// LDS 64 KB -> 2 blocks/CU. Each step reads 256 B CONTIGUOUS per feat row
// (vs 128 B at BK=32) -> 2x DRAM request granularity.
__global__ __launch_bounds__(256, 2) void gemm_kernel(
    const float* __restrict__ feat, const unsigned short* __restrict__ wta,
    const int* __restrict__ out_cnt, unsigned short* __restrict__ h) {
  __shared__ float As[2][64 * BK2];            // 16 KB each
  __shared__ unsigned short Bs[2][8192];       // 16 KB each

  const int t = threadIdx.x;
  const int lane = t & 63;
  const int wave = t >> 6;
  const int l15 = lane & 15;
  const int lg  = lane >> 4;
  const int rowbase = blockIdx.x * 64;

  const int r4 = lane >> 4;                    // row-within-quad for staging
  const int ch = lane & 15;                    // physical 16B chunk 0..15

  const int row = min(rowbase + wave * 16 + l15, NNODES - 1);
  const float s0 = rsqrtf(fmaxf((float)out_cnt[row], 1.0f));

  f32x4 acc[8];
#pragma unroll
  for (int c = 0; c < 8; ++c) acc[c] = (f32x4){0.f, 0.f, 0.f, 0.f};

  // A instr i (=wave*4+q, 0..15) covers rows 4i..4i+3, 1 KB each.
  // lane (r4,ch) writes physical chunk ch of row 4i+r4; fetches logical
  // chunk ch ^ (row&15)  ->  reader at logical lc reads physical lc^(row&15).
#define STAGE(buf, s)                                                          \
  {                                                                            \
    _Pragma("unroll")                                                          \
    for (int q = 0; q < 4; ++q) {                                              \
      int i = wave * 4 + q;                                                    \
      int lrow = 4 * i + r4;                                                   \
      int gr = min(rowbase + lrow, NNODES - 1);                                \
      int lc = ch ^ (lrow & 15);                                               \
      const float* ga = feat + (size_t)gr * INF + (s) * BK2 + lc * 4;          \
      gload_lds16(ga, &As[buf][i * 256]);                                      \
    }                                                                          \
    _Pragma("unroll")                                                          \
    for (int q = 0; q < 4; ++q) {                                              \
      int j = wave * 4 + q;                                                    \
      const unsigned short* gb =                                               \
          wta + (size_t)(s) * 8192 + j * 512 + lane * 8;                       \
      gload_lds16(gb, &Bs[buf][j * 512]);                                      \
    }                                                                          \
  }

  int buf = 0;
  STAGE(0, 0);
  __syncthreads();

  for (int s = 0; s < NK2; ++s) {
    if (s + 1 < NK2) STAGE(buf ^ 1, s + 1);

    const int r = wave * 16 + l15;
#pragma unroll
    for (int kk = 0; kk < 2; ++kk) {
      int lc0 = kk * 8 + lg * 2;
      f32x4 u = *(const f32x4*)&As[buf][r * BK2 + ((lc0) ^ l15) * 4];
      f32x4 v = *(const f32x4*)&As[buf][r * BK2 + ((lc0 + 1) ^ l15) * 4];
      bf16x8 a;
#pragma unroll
      for (int j = 0; j < 4; ++j) {
        a[j]     = (__bf16)(u[j] * s0);
        a[j + 4] = (__bf16)(v[j] * s0);
      }
#pragma unroll
      for (int c = 0; c < 8; ++c) {
        bf16x8 b = *(const bf16x8*)&Bs[buf][kk * 4096 + c * 512 + lane * 8];
        acc[c] = __builtin_amdgcn_mfma_f32_16x16x32_bf16(a, b, acc[c], 0, 0, 0);
      }
    }

    __syncthreads();
    buf ^= 1;
  }
#undef STAGE

  int rb = rowbase + wave * 16 + lg * 4;
#pragma unroll
  for (int r = 0; r < 4; ++r) {
    int orow = rb + r;
    if (orow < NNODES) {
#pragma unroll
      for (int c = 0; c < 8; ++c) {
        __bf16 bv = (__bf16)acc[c][r];
        h[(size_t)orow * OUTF + c * 16 + l15] = __builtin_bit_cast(unsigned short, bv);
      }
    }
  }
}

// ---------------- gather: 2 nodes/wave, register accumulation (R8 exact) ----
__device__ __forceinline__ float blo(unsigned int u) { return __uint_as_float(u << 16); }
__device__ __forceinline__ float bhi(unsigned int u) { return __uint_as_float(u & 0xFFFF0000u); }

__global__ __launch_bounds__(256) void gather_kernel(
    const int* __restrict__ rowptr, const int2* __restrict__ epair,
    const unsigned short* __restrict__ h, const float* __restrict__ bias,
    float* __restrict__ out) {
  const int lane = threadIdx.x & 63;
  const int half = lane >> 5;          // node select within pair
  const int grp  = (lane >> 4) & 1;    // edge interleave slot
  const int li   = lane & 15;          // feature slice
  const int wid  = (blockIdx.x * blockDim.x + threadIdx.x) >> 6;
  const int nw   = (gridDim.x * blockDim.x) >> 6;

  for (int p = wid; p < NNODES / 2; p += nw) {
    const int node = p * 2 + half;     // NNODES even
    const int beg = rowptr[node];
    const int end = rowptr[node + 1];

    float a0 = 0.f, a1 = 0.f, a2 = 0.f, a3 = 0.f;
    float a4 = 0.f, a5 = 0.f, a6 = 0.f, a7 = 0.f;

    int e = beg + grp;
#define GSTEP(pr)                                                              \
      {                                                                        \
        const unsigned int* hp =                                               \
            (const unsigned int*)(h + (size_t)(pr).x * OUTF) + li * 4;         \
        uint4 u = *(const uint4*)hp;                                           \
        float w = __int_as_float((pr).y);                                      \
        a0 += blo(u.x) * w; a1 += bhi(u.x) * w;                                \
        a2 += blo(u.y) * w; a3 += bhi(u.y) * w;                                \
        a4 += blo(u.z) * w; a5 += bhi(u.z) * w;                                \
        a6 += blo(u.w) * w; a7 += bhi(u.w) * w;                                \
      }
    for (; e + 6 < end; e += 8) {
      int2 p0 = epair[e];
      int2 p1 = epair[e + 2];
      int2 p2 = epair[e + 4];
      int2 p3 = epair[e + 6];
      GSTEP(p0); GSTEP(p1); GSTEP(p2); GSTEP(p3);
    }
    for (; e < end; e += 2) {
      int2 pr = epair[e];
      GSTEP(pr);
    }
#undef GSTEP

    // combine the two interleave slots (lanes differing in bit 4)
    a0 += __shfl_xor(a0, 16); a1 += __shfl_xor(a1, 16);
    a2 += __shfl_xor(a2, 16); a3 += __shfl_xor(a3, 16);
    a4 += __shfl_xor(a4, 16); a5 += __shfl_xor(a5, 16);
    a6 += __shfl_xor(a6, 16); a7 += __shfl_xor(a7, 16);

    if (grp == 0) {
      float sc = rsqrtf(fmaxf((float)(end - beg), 1.0f));
      f32x4 b0 = ((const f32x4*)bias)[li * 2];
      f32x4 b1 = ((const f32x4*)bias)[li * 2 + 1];
      f32x4 v0, v1;
      v0.x = a0 * sc + b0.x; v0.y = a1 * sc + b0.y;
      v0.z = a2 * sc + b0.z; v0.w = a3 * sc + b0.w;
      v1.x = a4 * sc + b1.x; v1.y = a5 * sc + b1.y;
      v1.z = a6 * sc + b1.z; v1.w = a7 * sc + b1.w;
      f32x4* op = (f32x4*)(out + (size_t)node * OUTF);
      op[li * 2] = v0;
      op[li * 2 + 1] = v1;
    }
  }
}

extern "C" void kernel_launch(void* const* d_in, const int* in_sizes, int n_in,
                              void* d_out, int out_size, void* d_ws, size_t ws_size,
                              hipStream_t stream) {
  const float* feat   = (const float*)d_in[0];
  const float* weight = (const float*)d_in[1];
  const float* bias   = (const float*)d_in[2];
  const float* ew     = (const float*)d_in[3];
  const int*   src    = (const int*)d_in[4];
  const int*   dst    = (const int*)d_in[5];
  float* out = (float*)d_out;
  char* ws = (char*)d_ws;

  int* out_cnt        = (int*)ws;                          // 400 KB
  int* rowptr         = (int*)(ws + 0x80000);              // 400 KB + 4
  int* bucket_cnt     = (int*)(ws + 0x100000);             // 1.6 KB
  int* bucket_base    = (int*)(ws + 0x101000);             // 1.6 KB
  unsigned short* wta = (unsigned short*)(ws + 0x110000);  // 128 KB
  int2* bucket        = (int2*)(ws + 0x140000);            // 16.0 MB
  int2* epair         = (int2*)(ws + 0x1200000);           // 12.8 MB
  unsigned short* h   = (unsigned short*)(ws + 0x2000000); // 25.6 MB

  hipMemsetAsync(out_cnt, 0, NNODES * sizeof(int), stream);
  hipMemsetAsync(bucket_cnt, 0, NB * sizeof(int), stream);

  wt_kernel<<<32, 256, 0, stream>>>(weight, wta);
  bucket_kernel<<<(NEDGES + SEG - 1) / SEG, 256, 0, stream>>>(src, dst, ew, out_cnt,
                                                              bucket_cnt, bucket);
  bscan_kernel<<<1, 512, 0, stream>>>(bucket_cnt, bucket_base, rowptr);
  csr_kernel<<<NB, 256, 0, stream>>>(bucket_cnt, bucket_base, bucket, rowptr, epair);
  gemm_kernel<<<(NNODES + 63) / 64, 256, 0, stream>>>(feat, wta, out_cnt, h);
  gather_kernel<<<2048, 256, 0, stream>>>(rowptr, epair, h, bias, out);
}

// Round 16
// 251.908 us; speedup vs baseline: 1.0760x; 1.0760x over previous
//
#include <hip/hip_runtime.h>
#include <hip/hip_bf16.h>

#define NNODES 100000
#define NEDGES 1600000
#define INF 512
#define OUTF 128
#define NB 391          // buckets of 256 nodes: bucket = dst >> 8
#define BCAP 5120       // mean 4096, sigma ~64 -> 16 sigma headroom
#define SEG 2048        // edges per block in bucket_kernel (782 blocks)
#define BK 32           // gemm k-step (floats)
#define NKSTEP (INF / BK)

typedef __attribute__((ext_vector_type(8))) __bf16 bf16x8;
typedef __attribute__((ext_vector_type(4))) float f32x4;

typedef const __attribute__((address_space(1))) unsigned int* gas_ptr;
typedef __attribute__((address_space(3))) unsigned int* las_ptr;

__device__ __forceinline__ void gload_lds16(const void* g, void* l) {
  __builtin_amdgcn_global_load_lds((gas_ptr)g, (las_ptr)l, 16, 0, 0);
}

// ---------------- weight f32 [512][128] -> bf16 fragment/lane-ordered -------
// short idx = kb*4096 + c8*512 + lane*8 + j  (lane = lg*16+l15)
//   value   = W[kb*32 + lg*8 + j][c8*16 + l15]
__global__ void wt_kernel(const float* __restrict__ w, unsigned short* __restrict__ wta) {
  int i = blockIdx.x * blockDim.x + threadIdx.x;   // 0..8191 int4s
  if (i >= 8192) return;
  int lane = i & 63;
  int c8   = (i >> 6) & 7;
  int kb   = i >> 9;
  int n = c8 * 16 + (lane & 15);
  int kbase = kb * 32 + (lane >> 4) * 8;
  unsigned short tmp[8];
#pragma unroll
  for (int j = 0; j < 8; ++j) {
    __bf16 b = (__bf16)(w[(size_t)(kbase + j) * OUTF + n]);
    tmp[j] = __builtin_bit_cast(unsigned short, b);
  }
  ((int4*)wta)[i] = *(int4*)tmp;
}

// ---------------- bucket edges by dst>>8, histogram src out-degree ----------
__global__ __launch_bounds__(256) void bucket_kernel(
    const int* __restrict__ src, const int* __restrict__ dst,
    const float* __restrict__ ew, int* __restrict__ out_cnt,
    int* __restrict__ bucket_cnt, int2* __restrict__ bucket) {
  __shared__ int hist[NB];
  __shared__ int base[NB];
  int t = threadIdx.x;
  for (int i = t; i < NB; i += 256) hist[i] = 0;
  __syncthreads();
  int e0 = blockIdx.x * SEG;
  int e1 = min(e0 + SEG, NEDGES);
  for (int e = e0 + t; e < e1; e += 256) {
    atomicAdd(&out_cnt[src[e]], 1);
    atomicAdd(&hist[dst[e] >> 8], 1);
  }
  __syncthreads();
  for (int i = t; i < NB; i += 256) {
    int c = hist[i];
    base[i] = c ? atomicAdd(&bucket_cnt[i], c) : 0;
    hist[i] = 0;                       // reuse as cursor
  }
  __syncthreads();
  for (int e = e0 + t; e < e1; e += 256) {
    int d = dst[e];
    int b = d >> 8;
    int r = atomicAdd(&hist[b], 1);
    int2 en;
    en.x = ((d & 255) << 17) | src[e];  // src < 2^17
    en.y = __float_as_int(ew[e]);
    bucket[(size_t)b * BCAP + base[b] + r] = en;
  }
}

// ---------------- bucket -> CSR (atomic segment alloc; no global scan) ------
// Block b grabs its epair segment with one atomicAdd(alloc, nb); per-node
// begin/end go to rowbeg/rowend (monotone only within a bucket, which is all
// the gather needs).
__global__ __launch_bounds__(256) void csr_kernel(
    const int* __restrict__ bucket_cnt, int* __restrict__ alloc,
    const int2* __restrict__ bucket, int* __restrict__ rowbeg,
    int* __restrict__ rowend, int2* __restrict__ epair) {
  __shared__ int hist[256];
  __shared__ int cur[256];
  __shared__ int sbase;
  int b = blockIdx.x;
  int t = threadIdx.x;
  int nb = bucket_cnt[b];
  if (t == 0) sbase = atomicAdd(alloc, nb);
  const int2* bk = bucket + (size_t)b * BCAP;
  hist[t] = 0;
  __syncthreads();
  for (int i = t; i < nb; i += 256) atomicAdd(&hist[bk[i].x >> 17], 1);
  __syncthreads();
  int v = hist[t];
  for (int off = 1; off < 256; off <<= 1) {
    int x = (t >= off) ? hist[t - off] : 0;
    __syncthreads();
    hist[t] += x;
    __syncthreads();
  }
  int excl = hist[t] - v;
  int bbase = sbase;
  int node = b * 256 + t;
  if (node < NNODES) {
    rowbeg[node] = bbase + excl;
    rowend[node] = bbase + excl + v;
  }
  cur[t] = excl;
  __syncthreads();
  for (int i = t; i < nb; i += 256) {
    int2 en = bk[i];
    int nl = en.x >> 17;
    int r = atomicAdd(&cur[nl], 1);
    epair[bbase + r] = make_int2(en.x & 0x1FFFF, en.y);
  }
}

// ---------------- h = (feat * rsqrt(out_deg)) @ W, LDS-staged MFMA ----------
// 64-row x 128-col tile, BK=32, 4 waves (one 16-row fragment each).
// LDS 32 KB -> 5 blocks/CU, 20 waves/CU. A dbuf chunk-XOR-swizzled via
// pre-swizzled global source; B dbuf lane-ordered (linear stage + read).
// Proven R8 structure (race-free: __syncthreads drains vmcnt).
__global__ __launch_bounds__(256, 4) void gemm_kernel(
    const float* __restrict__ feat, const unsigned short* __restrict__ wta,
    const int* __restrict__ out_cnt, unsigned short* __restrict__ h) {
  __shared__ float As[2][64 * BK];             // 8 KB each
  __shared__ unsigned short Bs[2][4096];       // 8 KB each

  const int t = threadIdx.x;
  const int lane = t & 63;
  const int wave = t >> 6;
  const int l15 = lane & 15;
  const int lg  = lane >> 4;
  const int rowbase = blockIdx.x * 64;

  const int srow_off = lane >> 3;              // 0..7
  const int schunk = (lane & 7) ^ srow_off;    // pre-swizzled source chunk

  const int row = min(rowbase + wave * 16 + l15, NNODES - 1);
  const float s0 = rsqrtf(fmaxf((float)out_cnt[row], 1.0f));

  f32x4 acc[8];
#pragma unroll
  for (int c = 0; c < 8; ++c) acc[c] = (f32x4){0.f, 0.f, 0.f, 0.f};

#define STAGE(buf, kb)                                                         \
  {                                                                            \
    _Pragma("unroll")                                                          \
    for (int q = 0; q < 2; ++q) {                                              \
      int i = wave * 2 + q;                                                    \
      int gr = min(rowbase + i * 8 + srow_off, NNODES - 1);                    \
      const float* ga = feat + (size_t)gr * INF + (kb) * BK + schunk * 4;      \
      gload_lds16(ga, &As[buf][i * 256]);                                      \
      const unsigned short* gb =                                               \
          wta + (size_t)(kb) * 4096 + i * 512 + lane * 8;                      \
      gload_lds16(gb, &Bs[buf][i * 512]);                                      \
    }                                                                          \
  }

  int buf = 0;
  STAGE(0, 0);
  __syncthreads();

  for (int kb = 0; kb < NKSTEP; ++kb) {
    if (kb + 1 < NKSTEP) STAGE(buf ^ 1, kb + 1);

    bf16x8 bfr[8];
#pragma unroll
    for (int c = 0; c < 8; ++c)
      bfr[c] = *(const bf16x8*)&Bs[buf][c * 512 + lane * 8];

    int r = wave * 16 + l15;
    int c0 = (lg * 2) ^ (l15 & 7);
    int c1 = (lg * 2 + 1) ^ (l15 & 7);
    f32x4 u = *(const f32x4*)&As[buf][r * 32 + c0 * 4];
    f32x4 v = *(const f32x4*)&As[buf][r * 32 + c1 * 4];
    bf16x8 a;
#pragma unroll
    for (int j = 0; j < 4; ++j) {
      a[j]     = (__bf16)(u[j] * s0);
      a[j + 4] = (__bf16)(v[j] * s0);
    }

#pragma unroll
    for (int c = 0; c < 8; ++c)
      acc[c] = __builtin_amdgcn_mfma_f32_16x16x32_bf16(a, bfr[c], acc[c], 0, 0, 0);

    __syncthreads();
    buf ^= 1;
  }
#undef STAGE

  int rb = rowbase + wave * 16 + lg * 4;
#pragma unroll
  for (int r = 0; r < 4; ++r) {
    int orow = rb + r;
    if (orow < NNODES) {
#pragma unroll
      for (int c = 0; c < 8; ++c) {
        __bf16 bv = (__bf16)acc[c][r];
        h[(size_t)orow * OUTF + c * 16 + l15] = __builtin_bit_cast(unsigned short, bv);
      }
    }
  }
}

// ---------------- gather: 2 nodes/wave, register accumulation (R8 exact) ----
__device__ __forceinline__ float blo(unsigned int u) { return __uint_as_float(u << 16); }
__device__ __forceinline__ float bhi(unsigned int u) { return __uint_as_float(u & 0xFFFF0000u); }

__global__ __launch_bounds__(256) void gather_kernel(
    const int* __restrict__ rowbeg, const int* __restrict__ rowend,
    const int2* __restrict__ epair, const unsigned short* __restrict__ h,
    const float* __restrict__ bias, float* __restrict__ out) {
  const int lane = threadIdx.x & 63;
  const int half = lane >> 5;          // node select within pair
  const int grp  = (lane >> 4) & 1;    // edge interleave slot
  const int li   = lane & 15;          // feature slice
  const int wid  = (blockIdx.x * blockDim.x + threadIdx.x) >> 6;
  const int nw   = (gridDim.x * blockDim.x) >> 6;

  for (int p = wid; p < NNODES / 2; p += nw) {
    const int node = p * 2 + half;     // NNODES even
    const int beg = rowbeg[node];
    const int end = rowend[node];

    float a0 = 0.f, a1 = 0.f, a2 = 0.f, a3 = 0.f;
    float a4 = 0.f, a5 = 0.f, a6 = 0.f, a7 = 0.f;

    int e = beg + grp;
#define GSTEP(pr)                                                              \
      {                                                                        \
        const unsigned int* hp =                                               \
            (const unsigned int*)(h + (size_t)(pr).x * OUTF) + li * 4;         \
        uint4 u = *(const uint4*)hp;                                           \
        float w = __int_as_float((pr).y);                                      \
        a0 += blo(u.x) * w; a1 += bhi(u.x) * w;                                \
        a2 += blo(u.y) * w; a3 += bhi(u.y) * w;                                \
        a4 += blo(u.z) * w; a5 += bhi(u.z) * w;                                \
        a6 += blo(u.w) * w; a7 += bhi(u.w) * w;                                \
      }
    for (; e + 6 < end; e += 8) {
      int2 p0 = epair[e];
      int2 p1 = epair[e + 2];
      int2 p2 = epair[e + 4];
      int2 p3 = epair[e + 6];
      GSTEP(p0); GSTEP(p1); GSTEP(p2); GSTEP(p3);
    }
    for (; e < end; e += 2) {
      int2 pr = epair[e];
      GSTEP(pr);
    }
#undef GSTEP

    // combine the two interleave slots (lanes differing in bit 4)
    a0 += __shfl_xor(a0, 16); a1 += __shfl_xor(a1, 16);
    a2 += __shfl_xor(a2, 16); a3 += __shfl_xor(a3, 16);
    a4 += __shfl_xor(a4, 16); a5 += __shfl_xor(a5, 16);
    a6 += __shfl_xor(a6, 16); a7 += __shfl_xor(a7, 16);

    if (grp == 0) {
      float sc = rsqrtf(fmaxf((float)(end - beg), 1.0f));
      f32x4 b0 = ((const f32x4*)bias)[li * 2];
      f32x4 b1 = ((const f32x4*)bias)[li * 2 + 1];
      f32x4 v0, v1;
      v0.x = a0 * sc + b0.x; v0.y = a1 * sc + b0.y;
      v0.z = a2 * sc + b0.z; v0.w = a3 * sc + b0.w;
      v1.x = a4 * sc + b1.x; v1.y = a5 * sc + b1.y;
      v1.z = a6 * sc + b1.z; v1.w = a7 * sc + b1.w;
      f32x4* op = (f32x4*)(out + (size_t)node * OUTF);
      op[li * 2] = v0;
      op[li * 2 + 1] = v1;
    }
  }
}

extern "C" void kernel_launch(void* const* d_in, const int* in_sizes, int n_in,
                              void* d_out, int out_size, void* d_ws, size_t ws_size,
                              hipStream_t stream) {
  const float* feat   = (const float*)d_in[0];
  const float* weight = (const float*)d_in[1];
  const float* bias   = (const float*)d_in[2];
  const float* ew     = (const float*)d_in[3];
  const int*   src    = (const int*)d_in[4];
  const int*   dst    = (const int*)d_in[5];
  float* out = (float*)d_out;
  char* ws = (char*)d_ws;

  // non-overlapping workspace map (sizes in bytes):
  int* out_cnt        = (int*)ws;                          // 0x000000 + 400 KB
  int* rowbeg         = (int*)(ws + 0x80000);              // 0x080000 + 400 KB
  int* rowend         = (int*)(ws + 0x100000);             // 0x100000 + 400 KB
  int* bucket_cnt     = (int*)(ws + 0x180000);             // NB ints + alloc
  int* alloc          = bucket_cnt + NB;
  unsigned short* wta = (unsigned short*)(ws + 0x190000);  // 128 KB
  int2* bucket        = (int2*)(ws + 0x1C0000);            // 16.0 MB
  int2* epair         = (int2*)(ws + 0x1200000);           // 12.8 MB
  unsigned short* h   = (unsigned short*)(ws + 0x2000000); // 25.6 MB

  hipMemsetAsync(out_cnt, 0, NNODES * sizeof(int), stream);
  hipMemsetAsync(bucket_cnt, 0, (NB + 1) * sizeof(int), stream);

  wt_kernel<<<32, 256, 0, stream>>>(weight, wta);
  bucket_kernel<<<(NEDGES + SEG - 1) / SEG, 256, 0, stream>>>(src, dst, ew, out_cnt,
                                                              bucket_cnt, bucket);
  csr_kernel<<<NB, 256, 0, stream>>>(bucket_cnt, alloc, bucket, rowbeg, rowend, epair);
  gemm_kernel<<<(NNODES + 63) / 64, 256, 0, stream>>>(feat, wta, out_cnt, h);
  gather_kernel<<<2048, 256, 0, stream>>>(rowbeg, rowend, epair, h, bias, out);
}